// Round 20
// baseline (191.344 us; speedup 1.0000x reference)
//
#include <hip/hip_runtime.h>

// MLPNodeLink: out[i,j] = relu(relu(relu([V1_i|V2_j]@W1+b1)@W2+b2)@W3+b3)
// h1[i,j] = relu(A[i] + B[j]), A=V1@W1[:128]+b1, B=V2@W1[128:]
// Round 20: tall-wave variant. BM=128, 16 waves of 128x32 (acc[4][1]=64
// AGPR) -> r16's L2 economics (16KB/CU-step, W2 1.05GB) AT 4 waves/SIMD
// (r16 stalled at 2 w/SIMD; r14's 4 w/SIMD doubled L2 rate). Budget: 64
// VGPR + 64 AGPR = 128 unified exactly -> 16 waves/CU. af ring-2, bfr
// ring-3. Epilogue: per-mt 128KB transpose buffer, one wave per row-pair.

typedef short bf16x8 __attribute__((ext_vector_type(8)));
typedef float f32x16 __attribute__((ext_vector_type(16)));

#define NROW 512
#define FDIM 128
#define HDIM 512

__device__ __forceinline__ unsigned int pk2(float x, float y) {
  unsigned int r;
  asm("v_cvt_pk_bf16_f32 %0, %1, %2" : "=v"(r) : "v"(x), "v"(y));
  return r;
}
__device__ __forceinline__ unsigned short f2bf(float x) {  // RTNE
  unsigned int u = __builtin_bit_cast(unsigned int, x);
  u += 0x7fffu + ((u >> 16) & 1u);
  return (unsigned short)(u >> 16);
}
__device__ __forceinline__ float bflo(unsigned int u) {
  return __builtin_bit_cast(float, u << 16);
}
__device__ __forceinline__ float bfhi(unsigned int u) {
  return __builtin_bit_cast(float, u & 0xffff0000u);
}

// ---- prep_ab: A[i][h] = V1[i]@W1[:128] + b1 (f32); B[j][h] (bf16) ----
__global__ __launch_bounds__(256) void prep_ab(
    const float* __restrict__ V1, const float* __restrict__ V2,
    const float* __restrict__ W1, const float* __restrict__ b1,
    float* __restrict__ Ap, unsigned short* __restrict__ Bpb) {
  __shared__ float sv[4 * FDIM];
  const int b = blockIdx.x;
  const int t = threadIdx.x;
  const bool isB = b >= 128;
  const int r0 = (b & 127) * 4;
  const float* V = isB ? V2 : V1;
  const float* W = W1 + (isB ? FDIM * HDIM : 0);
  for (int idx = t; idx < 4 * FDIM; idx += 256) sv[idx] = V[r0 * FDIM + idx];
  __syncthreads();
  float s[4][2] = {};
  for (int k = 0; k < FDIM; ++k) {
    const float w0 = W[k * HDIM + t];
    const float w1 = W[k * HDIM + t + 256];
#pragma unroll
    for (int r = 0; r < 4; ++r) {
      const float v = sv[r * FDIM + k];
      s[r][0] += v * w0;
      s[r][1] += v * w1;
    }
  }
  if (isB) {
#pragma unroll
    for (int r = 0; r < 4; ++r) {
      Bpb[(r0 + r) * HDIM + t] = f2bf(s[r][0]);
      Bpb[(r0 + r) * HDIM + t + 256] = f2bf(s[r][1]);
    }
  } else {
    const float bb0 = b1[t];
    const float bb1 = b1[t + 256];
#pragma unroll
    for (int r = 0; r < 4; ++r) {
      Ap[(r0 + r) * HDIM + t] = s[r][0] + bb0;
      Ap[(r0 + r) * HDIM + t + 256] = s[r][1] + bb1;
    }
  }
}

// ---- prep_w2: bf16 W2^T as [kc=k/8 (64)][n (512)] 16B chunks ----
__global__ __launch_bounds__(256) void prep_w2(const float* __restrict__ W2,
                                               unsigned short* __restrict__ W2T) {
  const int o = blockIdx.x * 256 + threadIdx.x;  // 128*256 = 32768 chunks
  const int kc = o >> 9;
  const int n = o & 511;
  unsigned int u[4];
#pragma unroll
  for (int e2 = 0; e2 < 4; ++e2)
    u[e2] = pk2(W2[(kc * 8 + 2 * e2) * HDIM + n], W2[(kc * 8 + 2 * e2 + 1) * HDIM + n]);
  *(uint4*)(W2T + (size_t)o * 8) = make_uint4(u[0], u[1], u[2], u[3]);
}

// ---- main: 128 pair-rows x 512 cols per block; 16 waves, each 128x32
// (4 mt x 1 nt of 32x32). K: 32 steps of 16; af ring-2, bfr ring-3.
__global__ __launch_bounds__(1024, 4) void mlp_main(
    const float* __restrict__ Ap, const unsigned short* __restrict__ Bpb,
    const unsigned short* __restrict__ W2T, const float* __restrict__ b2,
    const float* __restrict__ W3, const float* __restrict__ b3,
    float* __restrict__ out) {
  extern __shared__ char smem[];
  char* sA = smem;  // 128 rows * 1024B = 128KB; epilogue reuses all of it

  const int tid = threadIdx.x;
  const int wave = tid >> 6;  // 0..15 = col-slice
  const int lane = tid & 63;
  const int cl = lane & 31;   // frag row/col index
  const int hi = lane >> 5;   // k-octet select
  const int r15 = lane & 15;  // row&15 for af rows ((mt*32+cl)&15 = cl&15)

  const int m0 = blockIdx.x * 128;
  const int i = m0 >> 9;
  const int j0 = m0 & 511;

  // B chunk for this wave: n = wave*32 + cl; byte = n*16 + hi*8192 + s*16384
  const char* bbase = (const char*)W2T + (((wave << 5) + cl) << 4) + (hi << 13);

  // bfr prologue (before fill: L2 latency hides under fill VALU)
  bf16x8 af[2][4], bfr[3];
#pragma unroll
  for (int q = 0; q < 2; ++q) bfr[q] = *(const bf16x8*)(bbase + ((size_t)q << 14));

  // hoisted epilogue weights (nt=1: single col n per lane)
  const int ncol = (wave << 5) + cl;
  const float w30 = W3[2 * ncol];
  const float w31 = W3[2 * ncol + 1];
  const float bb = b2[ncol];
  const float bb3_0 = b3[0], bb3_1 = b3[1];

  // ---- fill: h1 tile (128 rows x 512 k) -> sA, bf16 Bp, 4-bit XOR swizzle
  {
    const int c = tid & 63;     // 16B chunk (8 k-elems)
    const int rsub = tid >> 6;  // 0..15
    const float4 a0 = *(const float4*)(Ap + i * HDIM + c * 8);
    const float4 a1 = *(const float4*)(Ap + i * HDIM + c * 8 + 4);
#pragma unroll
    for (int it = 0; it < 8; ++it) {
      const int row = it * 16 + rsub;
      const uint4 ub = *(const uint4*)(Bpb + (size_t)(j0 + row) * HDIM + c * 8);
      const uint4 v = make_uint4(
          pk2(fmaxf(a0.x + bflo(ub.x), 0.f), fmaxf(a0.y + bfhi(ub.x), 0.f)),
          pk2(fmaxf(a0.z + bflo(ub.y), 0.f), fmaxf(a0.w + bfhi(ub.y), 0.f)),
          pk2(fmaxf(a1.x + bflo(ub.z), 0.f), fmaxf(a1.y + bfhi(ub.z), 0.f)),
          pk2(fmaxf(a1.z + bflo(ub.w), 0.f), fmaxf(a1.w + bfhi(ub.w), 0.f)));
      *(uint4*)(sA + row * 1024 + ((c ^ (row & 15)) << 4)) = v;
    }
  }
  __syncthreads();

  // ---- pipelined K-loop: af ring-2 dist-1 (LDS), bfr ring-3 dist-2 (L2) --
  f32x16 acc[4];
#pragma unroll
  for (int mt = 0; mt < 4; ++mt)
#pragma unroll
    for (int q = 0; q < 16; ++q) acc[mt][q] = 0.f;

  const char* abase0 = sA + cl * 1024;  // mt at +mt*32768
  {
    const int off = (hi ^ r15) << 4;  // s=0
#pragma unroll
    for (int mt = 0; mt < 4; ++mt) af[0][mt] = *(const bf16x8*)(abase0 + mt * 32768 + off);
  }
#pragma unroll
  for (int s = 0; s < 32; ++s) {
    const int cur = s & 1;
    if (s < 31) {
      const int off = ((((s + 1) << 1) | hi) ^ r15) << 4;
#pragma unroll
      for (int mt = 0; mt < 4; ++mt)
        af[cur ^ 1][mt] = *(const bf16x8*)(abase0 + mt * 32768 + off);
    }
    if (s < 30) bfr[(s + 2) % 3] = *(const bf16x8*)(bbase + ((size_t)(s + 2) << 14));
    __builtin_amdgcn_s_setprio(1);
#pragma unroll
    for (int mt = 0; mt < 4; ++mt)
      acc[mt] = __builtin_amdgcn_mfma_f32_32x32x16_bf16(af[cur][mt], bfr[s % 3], acc[mt], 0, 0, 0);
    __builtin_amdgcn_s_setprio(0);
  }

  __syncthreads();  // sA reads done; 128KB buffer reused below

  // ---- epilogue: 4 mt rounds; [16 rpi][512 slot][16B] = 128KB buffer ----
#pragma unroll
  for (int mt = 0; mt < 4; ++mt) {
#pragma unroll
    for (int rp = 0; rp < 8; ++rp) {
      const int ra = 2 * rp;
      const float h0a = fmaxf(acc[mt][ra] + bb, 0.f);
      const float h0b = fmaxf(acc[mt][ra + 1] + bb, 0.f);
      const float4 v = make_float4(h0a * w30, h0a * w31, h0b * w30, h0b * w31);
      const int rpi = ((ra & 3) + 8 * (ra >> 2) + 4 * hi) >> 1;  // 0..15
      *(float4*)(smem + rpi * 8192 + (((wave << 5) + cl) << 4)) = v;
    }
    __syncthreads();
    {
      const int rpi = tid >> 6;  // one wave per row-pair
      const int sub = tid & 63;
      float4 s4 = make_float4(0.f, 0.f, 0.f, 0.f);
#pragma unroll
      for (int k = 0; k < 8; ++k) {
        const float4 v = *(const float4*)(smem + rpi * 8192 + ((sub + (k << 6)) << 4));
        s4.x += v.x; s4.y += v.y; s4.z += v.z; s4.w += v.w;
      }
#pragma unroll
      for (int d = 1; d < 64; d <<= 1) {
        s4.x += __shfl_xor(s4.x, d, 64);
        s4.y += __shfl_xor(s4.y, d, 64);
        s4.z += __shfl_xor(s4.z, d, 64);
        s4.w += __shfl_xor(s4.w, d, 64);
      }
      if (sub == 0) {
        const int rg = m0 + (mt << 5) + (rpi << 1);
        *(float4*)(out + rg * 2) =
            make_float4(fmaxf(s4.x + bb3_0, 0.f), fmaxf(s4.y + bb3_1, 0.f),
                        fmaxf(s4.z + bb3_0, 0.f), fmaxf(s4.w + bb3_1, 0.f));
      }
    }
    __syncthreads();
  }
}

extern "C" void kernel_launch(void* const* d_in, const int* in_sizes, int n_in,
                              void* d_out, int out_size, void* d_ws, size_t ws_size,
                              hipStream_t stream) {
  const float* V1 = (const float*)d_in[0];
  const float* V2 = (const float*)d_in[1];
  const float* W1 = (const float*)d_in[2];
  const float* b1 = (const float*)d_in[3];
  const float* W2 = (const float*)d_in[4];
  const float* b2 = (const float*)d_in[5];
  const float* W3 = (const float*)d_in[6];
  const float* b3 = (const float*)d_in[7];

  // ws layout: Ap (1MB f32) | Bpb (512KB bf16) | W2T (512KB bf16 tiled)
  float* Ap = (float*)d_ws;
  unsigned short* Bpb = (unsigned short*)(Ap + NROW * HDIM);
  unsigned short* W2T = Bpb + NROW * HDIM;

  const int smem_bytes = 131072;
  (void)hipFuncSetAttribute((const void*)mlp_main,
                            hipFuncAttributeMaxDynamicSharedMemorySize, smem_bytes);

  prep_ab<<<256, 256, 0, stream>>>(V1, V2, W1, b1, Ap, Bpb);
  prep_w2<<<128, 256, 0, stream>>>(W2, W2T);
  mlp_main<<<2048, 1024, smem_bytes, stream>>>(Ap, Bpb, W2T, b2, W3, b3, (float*)d_out);
}

// Round 21
// 185.619 us; speedup vs baseline: 1.0308x; 1.0308x over previous
//
#include <hip/hip_runtime.h>

// MLPNodeLink: out[i,j] = relu(relu(relu([V1_i|V2_j]@W1+b1)@W2+b2)@W3+b3)
// h1[i,j] = relu(A[i] + B[j]), A=V1@W1[:128]+b1, B=V2@W1[128:]
// Round 21: VMEM-free K-loop. W2 staged to LDS in bulk (global_load_lds,
// 64KB k-eighth dbuf) + h1 k-eighth dbuf (16KB x2) -> inner loop reads only
// LDS. Evidence r13-r20: per-step L2 loads serialize with MFMA at any ring
// depth; bulk staging overlaps across barriers via counted vmcnt (T3/T4).
// LDS 160KB exactly. Wave tile = r18's 128x64 (4mt x 2nt), acc 128 AGPR.

typedef short bf16x8 __attribute__((ext_vector_type(8)));
typedef float f32x16 __attribute__((ext_vector_type(16)));

#define NROW 512
#define FDIM 128
#define HDIM 512

__device__ __forceinline__ unsigned int pk2(float x, float y) {
  unsigned int r;
  asm("v_cvt_pk_bf16_f32 %0, %1, %2" : "=v"(r) : "v"(x), "v"(y));
  return r;
}
__device__ __forceinline__ unsigned short f2bf(float x) {  // RTNE
  unsigned int u = __builtin_bit_cast(unsigned int, x);
  u += 0x7fffu + ((u >> 16) & 1u);
  return (unsigned short)(u >> 16);
}
__device__ __forceinline__ float bflo(unsigned int u) {
  return __builtin_bit_cast(float, u << 16);
}
__device__ __forceinline__ float bfhi(unsigned int u) {
  return __builtin_bit_cast(float, u & 0xffff0000u);
}

// ---- prep_ab: A[i][h] = V1[i]@W1[:128] + b1 (f32); B[j][h] (bf16) ----
__global__ __launch_bounds__(256) void prep_ab(
    const float* __restrict__ V1, const float* __restrict__ V2,
    const float* __restrict__ W1, const float* __restrict__ b1,
    float* __restrict__ Ap, unsigned short* __restrict__ Bpb) {
  __shared__ float sv[4 * FDIM];
  const int b = blockIdx.x;
  const int t = threadIdx.x;
  const bool isB = b >= 128;
  const int r0 = (b & 127) * 4;
  const float* V = isB ? V2 : V1;
  const float* W = W1 + (isB ? FDIM * HDIM : 0);
  for (int idx = t; idx < 4 * FDIM; idx += 256) sv[idx] = V[r0 * FDIM + idx];
  __syncthreads();
  float s[4][2] = {};
  for (int k = 0; k < FDIM; ++k) {
    const float w0 = W[k * HDIM + t];
    const float w1 = W[k * HDIM + t + 256];
#pragma unroll
    for (int r = 0; r < 4; ++r) {
      const float v = sv[r * FDIM + k];
      s[r][0] += v * w0;
      s[r][1] += v * w1;
    }
  }
  if (isB) {
#pragma unroll
    for (int r = 0; r < 4; ++r) {
      Bpb[(r0 + r) * HDIM + t] = f2bf(s[r][0]);
      Bpb[(r0 + r) * HDIM + t + 256] = f2bf(s[r][1]);
    }
  } else {
    const float bb0 = b1[t];
    const float bb1 = b1[t + 256];
#pragma unroll
    for (int r = 0; r < 4; ++r) {
      Ap[(r0 + r) * HDIM + t] = s[r][0] + bb0;
      Ap[(r0 + r) * HDIM + t + 256] = s[r][1] + bb1;
    }
  }
}

// ---- prep_w2: bf16 W2^T as [kc=k/8 (64)][n (512)] 16B chunks ----
__global__ __launch_bounds__(256) void prep_w2(const float* __restrict__ W2,
                                               unsigned short* __restrict__ W2T) {
  const int o = blockIdx.x * 256 + threadIdx.x;  // 128*256 = 32768 chunks
  const int kc = o >> 9;
  const int n = o & 511;
  unsigned int u[4];
#pragma unroll
  for (int e2 = 0; e2 < 4; ++e2)
    u[e2] = pk2(W2[(kc * 8 + 2 * e2) * HDIM + n], W2[(kc * 8 + 2 * e2 + 1) * HDIM + n]);
  *(uint4*)(W2T + (size_t)o * 8) = make_uint4(u[0], u[1], u[2], u[3]);
}

// ---- main: 128 pair-rows x 512 cols per block; 8 waves; wave = 128x64
// (4mt x 2nt of 32x32). K in 8 eighths of 64; per eighth 4 steps of K=16.
// LDS: sB dbuf 64KB @0/@65536 ([kcl:8][n:512] 16B chunks, linear);
//      sA dbuf 16KB @131072/@147456 ([row:128][chunk c^(row&7):8] 16B).
__global__ __launch_bounds__(512, 2) void mlp_main(
    const float* __restrict__ Ap, const unsigned short* __restrict__ Bpb,
    const unsigned short* __restrict__ W2T, const float* __restrict__ b2,
    const float* __restrict__ W3, const float* __restrict__ b3,
    float* __restrict__ out) {
  extern __shared__ char smem[];

  const int tid = threadIdx.x;
  const int wave = tid >> 6;
  const int lane = tid & 63;
  const int cl = lane & 31;  // frag row/col index
  const int hi = lane >> 5;  // k-octet select
  const int frow = tid >> 2;        // fill row 0..127
  const int fc2 = (tid & 3) << 1;   // fill chunk pair 0,2,4,6

  const int m0 = blockIdx.x * 128;
  const int i = m0 >> 9;
  const int j0 = m0 & 511;

  // hoisted epilogue weights
  float w30[2], w31[2], bb[2];
#pragma unroll
  for (int nt = 0; nt < 2; ++nt) {
    const int n = (wave << 6) + (nt << 5) + cl;
    w30[nt] = W3[2 * n];
    w31[nt] = W3[2 * n + 1];
    bb[nt] = b2[n];
  }
  const float bb3_0 = b3[0], bb3_1 = b3[1];

  const int a_cl7 = cl & 7;  // af swizzle key (row&7 = cl&7 for all mt)
  const int bcol = ((wave << 6) + cl) << 4;  // bf byte offset of n (nt adds 32<<4)

  // ---- prologue: stage eighth 0 into buf0 ----
  {
    const int kh = fc2 * 8;  // e=0 k-offset for this thread's chunks
    const uint4 ub0 = *(const uint4*)(Bpb + (size_t)(j0 + frow) * HDIM + kh);
    const uint4 ub1 = *(const uint4*)(Bpb + (size_t)(j0 + frow) * HDIM + kh + 8);
    const float4 fa0 = *(const float4*)(Ap + i * HDIM + kh);
    const float4 fa1 = *(const float4*)(Ap + i * HDIM + kh + 4);
    const float4 fa2 = *(const float4*)(Ap + i * HDIM + kh + 8);
    const float4 fa3 = *(const float4*)(Ap + i * HDIM + kh + 12);
#pragma unroll
    for (int it = 0; it < 8; ++it) {
      const int off = (it * 512 + tid) * 16;
      __builtin_amdgcn_global_load_lds(
          (const __attribute__((address_space(1))) void*)((const char*)W2T + off),
          (__attribute__((address_space(3))) void*)(smem + off), 16, 0, 0);
    }
    const uint4 v0 = make_uint4(
        pk2(fmaxf(fa0.x + bflo(ub0.x), 0.f), fmaxf(fa0.y + bfhi(ub0.x), 0.f)),
        pk2(fmaxf(fa0.z + bflo(ub0.y), 0.f), fmaxf(fa0.w + bfhi(ub0.y), 0.f)),
        pk2(fmaxf(fa1.x + bflo(ub0.z), 0.f), fmaxf(fa1.y + bfhi(ub0.z), 0.f)),
        pk2(fmaxf(fa1.z + bflo(ub0.w), 0.f), fmaxf(fa1.w + bfhi(ub0.w), 0.f)));
    const uint4 v1 = make_uint4(
        pk2(fmaxf(fa2.x + bflo(ub1.x), 0.f), fmaxf(fa2.y + bfhi(ub1.x), 0.f)),
        pk2(fmaxf(fa2.z + bflo(ub1.y), 0.f), fmaxf(fa2.w + bfhi(ub1.y), 0.f)),
        pk2(fmaxf(fa3.x + bflo(ub1.z), 0.f), fmaxf(fa3.y + bfhi(ub1.z), 0.f)),
        pk2(fmaxf(fa3.z + bflo(ub1.w), 0.f), fmaxf(fa3.w + bfhi(ub1.w), 0.f)));
    char* sA0 = smem + 131072;
    *(uint4*)(sA0 + frow * 128 + ((fc2 ^ (frow & 7)) << 4)) = v0;
    *(uint4*)(sA0 + frow * 128 + (((fc2 + 1) ^ (frow & 7)) << 4)) = v1;
  }
  __syncthreads();

  f32x16 acc[4][2];
#pragma unroll
  for (int mt = 0; mt < 4; ++mt)
#pragma unroll
    for (int nt = 0; nt < 2; ++nt)
#pragma unroll
      for (int q = 0; q < 16; ++q) acc[mt][nt][q] = 0.f;

#pragma unroll 1
  for (int e = 0; e < 8; ++e) {
    char* sBc = smem + (e & 1) * 65536;
    char* sAc = smem + 131072 + (e & 1) * 16384;
    char* sBn = smem + ((e & 1) ^ 1) * 65536;
    char* sAn = smem + 131072 + ((e & 1) ^ 1) * 16384;

    // T14 split: issue next-eighth reg loads FIRST (oldest in vmcnt queue)
    uint4 ub0, ub1;
    float4 fa0, fa1, fa2, fa3;
    if (e < 7) {
      const int kh = (e + 1) * 64 + fc2 * 8;
      ub0 = *(const uint4*)(Bpb + (size_t)(j0 + frow) * HDIM + kh);
      ub1 = *(const uint4*)(Bpb + (size_t)(j0 + frow) * HDIM + kh + 8);
      fa0 = *(const float4*)(Ap + i * HDIM + kh);
      fa1 = *(const float4*)(Ap + i * HDIM + kh + 4);
      fa2 = *(const float4*)(Ap + i * HDIM + kh + 8);
      fa3 = *(const float4*)(Ap + i * HDIM + kh + 12);
      // bulk-stage next W2 eighth into sBn
      const char* gsrc = (const char*)W2T + ((size_t)(e + 1) << 16);
#pragma unroll
      for (int it = 0; it < 8; ++it) {
        const int off = (it * 512 + tid) * 16;
        __builtin_amdgcn_global_load_lds(
            (const __attribute__((address_space(1))) void*)(gsrc + off),
            (__attribute__((address_space(3))) void*)(sBn + off), 16, 0, 0);
      }
    }

    // ---- compute eighth e: 4 steps of K=16, LDS-only operands ----
    const char* alane = sAc + cl * 128;  // mt row at +mt*4096
    bf16x8 af[2][4], bf[2][2];
    {
      const int co = (hi ^ a_cl7) << 4;
#pragma unroll
      for (int mt = 0; mt < 4; ++mt)
        af[0][mt] = *(const bf16x8*)(alane + mt * 4096 + co);
#pragma unroll
      for (int nt = 0; nt < 2; ++nt)
        bf[0][nt] = *(const bf16x8*)(sBc + (hi << 13) + bcol + (nt << 9));
    }
#pragma unroll
    for (int sl = 0; sl < 4; ++sl) {
      const int cur = sl & 1;
      if (sl < 3) {
        const int kcl = ((sl + 1) << 1) | hi;
        const int co = (kcl ^ a_cl7) << 4;
#pragma unroll
        for (int mt = 0; mt < 4; ++mt)
          af[cur ^ 1][mt] = *(const bf16x8*)(alane + mt * 4096 + co);
#pragma unroll
        for (int nt = 0; nt < 2; ++nt)
          bf[cur ^ 1][nt] = *(const bf16x8*)(sBc + (kcl << 13) + bcol + (nt << 9));
      }
      __builtin_amdgcn_s_setprio(1);
#pragma unroll
      for (int nt = 0; nt < 2; ++nt)
#pragma unroll
        for (int mt = 0; mt < 4; ++mt)
          acc[mt][nt] = __builtin_amdgcn_mfma_f32_32x32x16_bf16(af[cur][mt], bf[cur][nt],
                                                                acc[mt][nt], 0, 0, 0);
      __builtin_amdgcn_s_setprio(0);
    }

    // pack + write next sA eighth (reg loads have had the whole compute)
    if (e < 7) {
      const uint4 v0 = make_uint4(
          pk2(fmaxf(fa0.x + bflo(ub0.x), 0.f), fmaxf(fa0.y + bfhi(ub0.x), 0.f)),
          pk2(fmaxf(fa0.z + bflo(ub0.y), 0.f), fmaxf(fa0.w + bfhi(ub0.y), 0.f)),
          pk2(fmaxf(fa1.x + bflo(ub0.z), 0.f), fmaxf(fa1.y + bfhi(ub0.z), 0.f)),
          pk2(fmaxf(fa1.z + bflo(ub0.w), 0.f), fmaxf(fa1.w + bfhi(ub0.w), 0.f)));
      const uint4 v1 = make_uint4(
          pk2(fmaxf(fa2.x + bflo(ub1.x), 0.f), fmaxf(fa2.y + bfhi(ub1.x), 0.f)),
          pk2(fmaxf(fa2.z + bflo(ub1.y), 0.f), fmaxf(fa2.w + bfhi(ub1.y), 0.f)),
          pk2(fmaxf(fa3.x + bflo(ub1.z), 0.f), fmaxf(fa3.y + bfhi(ub1.z), 0.f)),
          pk2(fmaxf(fa3.z + bflo(ub1.w), 0.f), fmaxf(fa3.w + bfhi(ub1.w), 0.f)));
      *(uint4*)(sAn + frow * 128 + ((fc2 ^ (frow & 7)) << 4)) = v0;
      *(uint4*)(sAn + frow * 128 + (((fc2 + 1) ^ (frow & 7)) << 4)) = v1;
    }
    __syncthreads();  // drains vmcnt (gloads) + lgkmcnt; swap buffers
  }

  // ---- epilogue: 2 rounds; buffers = dead sB halves (2 x 64KB) ----
#pragma unroll
  for (int rnd = 0; rnd < 2; ++rnd) {
#pragma unroll
    for (int ml = 0; ml < 2; ++ml) {
      const int mt = rnd * 2 + ml;
      char* ebuf = smem + ml * 65536;  // [16 rp][256 slot][16B]
#pragma unroll
      for (int rp = 0; rp < 8; ++rp) {
        const int ra = 2 * rp;
        const float h0a = fmaxf(acc[mt][0][ra] + bb[0], 0.f);
        const float h1a = fmaxf(acc[mt][1][ra] + bb[1], 0.f);
        const float h0b = fmaxf(acc[mt][0][ra + 1] + bb[0], 0.f);
        const float h1b = fmaxf(acc[mt][1][ra + 1] + bb[1], 0.f);
        const float4 v =
            make_float4(h0a * w30[0] + h1a * w30[1], h0a * w31[0] + h1a * w31[1],
                        h0b * w30[0] + h1b * w30[1], h0b * w31[0] + h1b * w31[1]);
        const int rpi = ((ra & 3) + 8 * (ra >> 2) + 4 * hi) >> 1;
        *(float4*)(ebuf + rpi * 4096 + (((wave << 5) + cl) << 4)) = v;
      }
    }
    __syncthreads();
    {
      const int ml = tid >> 8;
      const int t2 = tid & 255;
      const int rpi = t2 >> 4;
      const int sub = t2 & 15;
      const char* ebuf = smem + ml * 65536;
      float4 s4 = make_float4(0.f, 0.f, 0.f, 0.f);
#pragma unroll
      for (int k = 0; k < 16; ++k) {
        const float4 v = *(const float4*)(ebuf + rpi * 4096 + ((sub + (k << 4)) << 4));
        s4.x += v.x; s4.y += v.y; s4.z += v.z; s4.w += v.w;
      }
#pragma unroll
      for (int d = 1; d < 16; d <<= 1) {
        s4.x += __shfl_xor(s4.x, d, 64);
        s4.y += __shfl_xor(s4.y, d, 64);
        s4.z += __shfl_xor(s4.z, d, 64);
        s4.w += __shfl_xor(s4.w, d, 64);
      }
      if (sub == 0) {
        const int rg = m0 + ((rnd * 2 + ml) << 5) + (rpi << 1);
        *(float4*)(out + rg * 2) =
            make_float4(fmaxf(s4.x + bb3_0, 0.f), fmaxf(s4.y + bb3_1, 0.f),
                        fmaxf(s4.z + bb3_0, 0.f), fmaxf(s4.w + bb3_1, 0.f));
      }
    }
    __syncthreads();
  }
}

extern "C" void kernel_launch(void* const* d_in, const int* in_sizes, int n_in,
                              void* d_out, int out_size, void* d_ws, size_t ws_size,
                              hipStream_t stream) {
  const float* V1 = (const float*)d_in[0];
  const float* V2 = (const float*)d_in[1];
  const float* W1 = (const float*)d_in[2];
  const float* b1 = (const float*)d_in[3];
  const float* W2 = (const float*)d_in[4];
  const float* b2 = (const float*)d_in[5];
  const float* W3 = (const float*)d_in[6];
  const float* b3 = (const float*)d_in[7];

  // ws layout: Ap (1MB f32) | Bpb (512KB bf16) | W2T (512KB bf16 tiled)
  float* Ap = (float*)d_ws;
  unsigned short* Bpb = (unsigned short*)(Ap + NROW * HDIM);
  unsigned short* W2T = Bpb + NROW * HDIM;

  const int smem_bytes = 163840;  // sB 2x64KB + sA 2x16KB
  (void)hipFuncSetAttribute((const void*)mlp_main,
                            hipFuncAttributeMaxDynamicSharedMemorySize, smem_bytes);

  prep_ab<<<256, 256, 0, stream>>>(V1, V2, W1, b1, Ap, Bpb);
  prep_w2<<<128, 256, 0, stream>>>(W2, W2T);
  mlp_main<<<2048, 512, smem_bytes, stream>>>(Ap, Bpb, W2T, b2, W3, b3, (float*)d_out);
}

// Round 22
// 143.559 us; speedup vs baseline: 1.3329x; 1.2930x over previous
//
#include <hip/hip_runtime.h>

// MLPNodeLink: out[i,j] = relu(relu(relu([V1_i|V2_j]@W1+b1)@W2+b2)@W3+b3)
// h1[i,j] = relu(A[i] + B[j]), A=V1@W1[:128]+b1, B=V2@W1[128:]
// Round 22: restore r18 (measured optimum 144.9us; r21 structural rewrite
// regressed like r11/r12/r14/r20 -- ledger says r18 structure is the local
// optimum). Only delta: prep_ab+prep_w2 fused into one launch (384 blocks).
// mlp_main byte-identical to r18: BM=128, 8 waves of 128x64 (4mt x 2nt),
// af ring-2, bfr ring-5 dist-4, setprio on MFMA cluster, bf16 Bpb fill,
// 2-round epilogue.

typedef short bf16x8 __attribute__((ext_vector_type(8)));
typedef float f32x16 __attribute__((ext_vector_type(16)));

#define NROW 512
#define FDIM 128
#define HDIM 512

__device__ __forceinline__ unsigned int pk2(float x, float y) {
  unsigned int r;
  asm("v_cvt_pk_bf16_f32 %0, %1, %2" : "=v"(r) : "v"(x), "v"(y));
  return r;
}
__device__ __forceinline__ unsigned short f2bf(float x) {  // RTNE
  unsigned int u = __builtin_bit_cast(unsigned int, x);
  u += 0x7fffu + ((u >> 16) & 1u);
  return (unsigned short)(u >> 16);
}
__device__ __forceinline__ float bflo(unsigned int u) {
  return __builtin_bit_cast(float, u << 16);
}
__device__ __forceinline__ float bfhi(unsigned int u) {
  return __builtin_bit_cast(float, u & 0xffff0000u);
}

// ---- fused prep: blocks 0..255 -> A/B rows; 256..383 -> W2 retile ----
// A[i][h] = V1[i]@W1[:128] + b1 (f32); B[j][h] = V2[j]@W1[128:] (bf16);
// W2T chunk o = kc*512+n holds W2[kc*8+e][n], e=0..7 (bf16).
__global__ __launch_bounds__(256) void prep_fused(
    const float* __restrict__ V1, const float* __restrict__ V2,
    const float* __restrict__ W1, const float* __restrict__ b1,
    const float* __restrict__ W2, float* __restrict__ Ap,
    unsigned short* __restrict__ Bpb, unsigned short* __restrict__ W2T) {
  const int b = blockIdx.x;
  const int t = threadIdx.x;
  if (b >= 256) {  // ---- W2 retile role ----
    const int o = (b - 256) * 256 + t;  // 128*256 = 32768 chunks
    const int kc = o >> 9;
    const int n = o & 511;
    unsigned int u[4];
#pragma unroll
    for (int e2 = 0; e2 < 4; ++e2)
      u[e2] = pk2(W2[(kc * 8 + 2 * e2) * HDIM + n], W2[(kc * 8 + 2 * e2 + 1) * HDIM + n]);
    *(uint4*)(W2T + (size_t)o * 8) = make_uint4(u[0], u[1], u[2], u[3]);
    return;
  }
  // ---- A/B role ----
  __shared__ float sv[4 * FDIM];
  const bool isB = b >= 128;
  const int r0 = (b & 127) * 4;
  const float* V = isB ? V2 : V1;
  const float* W = W1 + (isB ? FDIM * HDIM : 0);
  for (int idx = t; idx < 4 * FDIM; idx += 256) sv[idx] = V[r0 * FDIM + idx];
  __syncthreads();
  float s[4][2] = {};
  for (int k = 0; k < FDIM; ++k) {
    const float w0 = W[k * HDIM + t];
    const float w1 = W[k * HDIM + t + 256];
#pragma unroll
    for (int r = 0; r < 4; ++r) {
      const float v = sv[r * FDIM + k];
      s[r][0] += v * w0;
      s[r][1] += v * w1;
    }
  }
  if (isB) {
#pragma unroll
    for (int r = 0; r < 4; ++r) {
      Bpb[(r0 + r) * HDIM + t] = f2bf(s[r][0]);
      Bpb[(r0 + r) * HDIM + t + 256] = f2bf(s[r][1]);
    }
  } else {
    const float bb0 = b1[t];
    const float bb1 = b1[t + 256];
#pragma unroll
    for (int r = 0; r < 4; ++r) {
      Ap[(r0 + r) * HDIM + t] = s[r][0] + bb0;
      Ap[(r0 + r) * HDIM + t + 256] = s[r][1] + bb1;
    }
  }
}

// ---- main: 128 pair-rows x 512 cols per block; 8 waves; wave = 128x64 tile
// as 4 mt x 2 nt frags of 32x32. K: 32 steps of 16; af ring-2, bfr dist-4.
__global__ __launch_bounds__(512, 2) void mlp_main(
    const float* __restrict__ Ap, const unsigned short* __restrict__ Bpb,
    const unsigned short* __restrict__ W2T, const float* __restrict__ b2,
    const float* __restrict__ W3, const float* __restrict__ b3,
    float* __restrict__ out) {
  extern __shared__ char smem[];
  char* sA = smem;  // 128 rows * 1024B = 128KB; epilogue reuses both halves

  const int tid = threadIdx.x;
  const int wave = tid >> 6;
  const int lane = tid & 63;
  const int cl = lane & 31;   // frag row/col index
  const int hi = lane >> 5;   // k-octet select
  const int r15 = lane & 15;  // row&15 for af rows

  const int m0 = blockIdx.x * 128;
  const int i = m0 >> 9;
  const int j0 = m0 & 511;

  const char* bbase = (const char*)W2T + (((wave << 6) + cl) << 4) + (hi << 13);

  // bfr prologue (issued BEFORE fill so L2 latency hides under fill VALU)
  bf16x8 af[2][4], bfr[5][2];
#pragma unroll
  for (int q = 0; q < 4; ++q) {
    const char* bp = bbase + ((size_t)q << 14);
    bfr[q][0] = *(const bf16x8*)(bp);
    bfr[q][1] = *(const bf16x8*)(bp + (1 << 9));
  }
  // hoisted epilogue weights
  float w30[2], w31[2], bb[2];
#pragma unroll
  for (int nt = 0; nt < 2; ++nt) {
    const int n = (wave << 6) + (nt << 5) + cl;
    w30[nt] = W3[2 * n];
    w31[nt] = W3[2 * n + 1];
    bb[nt] = b2[n];
  }
  const float bb3_0 = b3[0], bb3_1 = b3[1];

  // ---- fill: h1 tile (128 rows x 512 k) -> sA, bf16 Bp, 4-bit XOR swizzle
  {
    const int c = tid & 63;     // 16B chunk (8 k-elems)
    const int rsub = tid >> 6;  // 0..7
    const float4 a0 = *(const float4*)(Ap + i * HDIM + c * 8);
    const float4 a1 = *(const float4*)(Ap + i * HDIM + c * 8 + 4);
#pragma unroll
    for (int it = 0; it < 16; ++it) {
      const int row = it * 8 + rsub;
      const uint4 ub = *(const uint4*)(Bpb + (size_t)(j0 + row) * HDIM + c * 8);
      const uint4 v = make_uint4(
          pk2(fmaxf(a0.x + bflo(ub.x), 0.f), fmaxf(a0.y + bfhi(ub.x), 0.f)),
          pk2(fmaxf(a0.z + bflo(ub.y), 0.f), fmaxf(a0.w + bfhi(ub.y), 0.f)),
          pk2(fmaxf(a1.x + bflo(ub.z), 0.f), fmaxf(a1.y + bfhi(ub.z), 0.f)),
          pk2(fmaxf(a1.z + bflo(ub.w), 0.f), fmaxf(a1.w + bfhi(ub.w), 0.f)));
      *(uint4*)(sA + row * 1024 + ((c ^ (row & 15)) << 4)) = v;
    }
  }
  __syncthreads();

  // ---- pipelined K-loop: af ring-2 dist-1 (LDS), bfr ring-5 dist-4 (L2) --
  f32x16 acc[4][2];
#pragma unroll
  for (int mt = 0; mt < 4; ++mt)
#pragma unroll
    for (int nt = 0; nt < 2; ++nt)
#pragma unroll
      for (int q = 0; q < 16; ++q) acc[mt][nt][q] = 0.f;

  const char* abase0 = sA + cl * 1024;  // mt at +mt*32768
  {
    const int off = (hi ^ r15) << 4;  // s=0
#pragma unroll
    for (int mt = 0; mt < 4; ++mt) af[0][mt] = *(const bf16x8*)(abase0 + mt * 32768 + off);
  }
#pragma unroll
  for (int s = 0; s < 32; ++s) {
    const int cur = s & 1;
    if (s < 31) {
      const int off = ((((s + 1) << 1) | hi) ^ r15) << 4;
#pragma unroll
      for (int mt = 0; mt < 4; ++mt)
        af[cur ^ 1][mt] = *(const bf16x8*)(abase0 + mt * 32768 + off);
    }
    if (s < 28) {
      const char* bp = bbase + ((size_t)(s + 4) << 14);
      bfr[(s + 4) % 5][0] = *(const bf16x8*)(bp);
      bfr[(s + 4) % 5][1] = *(const bf16x8*)(bp + (1 << 9));
    }
    __builtin_amdgcn_s_setprio(1);
#pragma unroll
    for (int nt = 0; nt < 2; ++nt)
#pragma unroll
      for (int mt = 0; mt < 4; ++mt)
        acc[mt][nt] = __builtin_amdgcn_mfma_f32_32x32x16_bf16(af[cur][mt], bfr[s % 5][nt],
                                                              acc[mt][nt], 0, 0, 0);
    __builtin_amdgcn_s_setprio(0);
  }

  __syncthreads();  // sA reads done; both 64KB halves reused below

  // ---- epilogue: 2 rounds; round r handles mt = 2r, 2r+1 in parallel ----
#pragma unroll
  for (int rnd = 0; rnd < 2; ++rnd) {
#pragma unroll
    for (int ml = 0; ml < 2; ++ml) {
      const int mt = rnd * 2 + ml;
      char* ebuf = smem + ml * 65536;  // [16 rp][256 slot][16B]
#pragma unroll
      for (int rp = 0; rp < 8; ++rp) {
        const int ra = 2 * rp;
        const float h0a = fmaxf(acc[mt][0][ra] + bb[0], 0.f);
        const float h1a = fmaxf(acc[mt][1][ra] + bb[1], 0.f);
        const float h0b = fmaxf(acc[mt][0][ra + 1] + bb[0], 0.f);
        const float h1b = fmaxf(acc[mt][1][ra + 1] + bb[1], 0.f);
        const float4 v =
            make_float4(h0a * w30[0] + h1a * w30[1], h0a * w31[0] + h1a * w31[1],
                        h0b * w30[0] + h1b * w30[1], h0b * w31[0] + h1b * w31[1]);
        const int rpi = ((ra & 3) + 8 * (ra >> 2) + 4 * hi) >> 1;
        *(float4*)(ebuf + rpi * 4096 + (((wave << 5) + cl) << 4)) = v;
      }
    }
    __syncthreads();
    {
      const int ml = tid >> 8;  // 0/1 -> which mt of this round
      const int t2 = tid & 255;
      const int rpi = t2 >> 4;  // 0..15
      const int sub = t2 & 15;  // 16 threads per rowpair
      const char* ebuf = smem + ml * 65536;
      float4 s4 = make_float4(0.f, 0.f, 0.f, 0.f);
#pragma unroll
      for (int k = 0; k < 16; ++k) {
        const float4 v = *(const float4*)(ebuf + rpi * 4096 + ((sub + (k << 4)) << 4));
        s4.x += v.x; s4.y += v.y; s4.z += v.z; s4.w += v.w;
      }
#pragma unroll
      for (int d = 1; d < 16; d <<= 1) {
        s4.x += __shfl_xor(s4.x, d, 64);
        s4.y += __shfl_xor(s4.y, d, 64);
        s4.z += __shfl_xor(s4.z, d, 64);
        s4.w += __shfl_xor(s4.w, d, 64);
      }
      if (sub == 0) {
        const int rg = m0 + ((rnd * 2 + ml) << 5) + (rpi << 1);
        *(float4*)(out + rg * 2) =
            make_float4(fmaxf(s4.x + bb3_0, 0.f), fmaxf(s4.y + bb3_1, 0.f),
                        fmaxf(s4.z + bb3_0, 0.f), fmaxf(s4.w + bb3_1, 0.f));
      }
    }
    __syncthreads();
  }
}

extern "C" void kernel_launch(void* const* d_in, const int* in_sizes, int n_in,
                              void* d_out, int out_size, void* d_ws, size_t ws_size,
                              hipStream_t stream) {
  const float* V1 = (const float*)d_in[0];
  const float* V2 = (const float*)d_in[1];
  const float* W1 = (const float*)d_in[2];
  const float* b1 = (const float*)d_in[3];
  const float* W2 = (const float*)d_in[4];
  const float* b2 = (const float*)d_in[5];
  const float* W3 = (const float*)d_in[6];
  const float* b3 = (const float*)d_in[7];

  // ws layout: Ap (1MB f32) | Bpb (512KB bf16) | W2T (512KB bf16 tiled)
  float* Ap = (float*)d_ws;
  unsigned short* Bpb = (unsigned short*)(Ap + NROW * HDIM);
  unsigned short* W2T = Bpb + NROW * HDIM;

  const int smem_bytes = 131072;
  (void)hipFuncSetAttribute((const void*)mlp_main,
                            hipFuncAttributeMaxDynamicSharedMemorySize, smem_bytes);

  prep_fused<<<384, 256, 0, stream>>>(V1, V2, W1, b1, W2, Ap, Bpb, W2T);
  mlp_main<<<2048, 512, smem_bytes, stream>>>(Ap, Bpb, W2T, b2, W3, b3, (float*)d_out);
}